// Round 13
// baseline (668.028 us; speedup 1.0000x reference)
//
#include <hip/hip_runtime.h>

typedef __attribute__((ext_vector_type(4))) float f32x4;
typedef __attribute__((ext_vector_type(8))) short s16x8;
typedef __attribute__((ext_vector_type(4))) short s16x4;
typedef __attribute__((ext_vector_type(4))) unsigned u32x4;
typedef __attribute__((ext_vector_type(2))) unsigned u32x2;

__device__ __forceinline__ short f2bf(float f) {          // RNE (weights/scalars)
    unsigned u = __builtin_bit_cast(unsigned, f);
    u += 0x7fffu + ((u >> 16) & 1u);
    return (short)(u >> 16);
}
__device__ __forceinline__ unsigned cvt_pk_bf16(float a, float b) {  // lo=a, hi=b (RNE)
    unsigned r;
    asm("v_cvt_pk_bf16_f32 %0, %1, %2" : "=v"(r) : "v"(a), "v"(b));
    return r;
}
__device__ __forceinline__ s16x4 pack4(float v0, float v1, float v2, float v3) {
    u32x2 p;
    p[0] = cvt_pk_bf16(v0, v1);
    p[1] = cvt_pk_bf16(v2, v3);
    return __builtin_bit_cast(s16x4, p);
}

// ---------------------------------------------------------------------------
// Weight prep: transpose to [n][k] bf16. W1T zero-padded to K=32 for MFMA L1.
// ---------------------------------------------------------------------------
__global__ void k_prep(const float* __restrict__ W1,
                       const float* __restrict__ W2, const float* __restrict__ W3,
                       const float* __restrict__ W4,
                       const float* __restrict__ Wc1, const float* __restrict__ Wc2,
                       const float* __restrict__ Wc3, const float* __restrict__ Wc4,
                       short* __restrict__ W1T,
                       short* __restrict__ W2T, short* __restrict__ W3T,
                       float* __restrict__ W4T,
                       short* __restrict__ Wc1T, short* __restrict__ Wc2T,
                       short* __restrict__ Wc3T, short* __restrict__ Wc4T)
{
    int tid = blockIdx.x * 256 + threadIdx.x;   // 65536 total
    if (tid < 4096) {   // W1T: [n<128][k<32], only k<4 nonzero
        int n = tid >> 5, k = tid & 31;
        W1T[tid] = (k < 4) ? f2bf(W1[k * 128 + n]) : (short)0;
    }
    if (tid < 16384) {  // W2T/W3T: [n<128][k<128]
        int n = tid >> 7, k = tid & 127;
        W2T[tid] = f2bf(W2[k * 128 + n]);
        W3T[tid] = f2bf(W3[k * 128 + n]);
    }
    if (tid < 256) {    // W4T: [s<2][k<128] fp32
        int s = tid >> 7, k = tid & 127;
        W4T[tid] = W4[k * 2 + s];
    }
    if (tid < 8192) {   // Wc1T: [n<128][c<64]
        int n = tid >> 6, c = tid & 63;
        Wc1T[tid] = f2bf(Wc1[c * 128 + n]);
    }
    if (tid < 32768) {  // Wc2T: [n<256][k<128]
        int n = tid >> 7, k = tid & 127;
        Wc2T[tid] = f2bf(Wc2[k * 256 + n]);
    }
    if (tid < 65536) {  // Wc3T: [n<256][k<256]
        int n = tid >> 8, k = tid & 255;
        Wc3T[tid] = f2bf(Wc3[k * 256 + n]);
    }
    if (tid < 8192) {   // Wc4T: [n<32][k<256]
        int n = tid >> 8, k = tid & 255;
        Wc4T[tid] = f2bf(Wc4[k * 32 + n]);
    }
}

// ---------------------------------------------------------------------------
// Phase-1, register-resident: 4 waves x 16 edge-rows; each wave computes all
// 128 features of its rows entirely in registers. D-frag -> next B-frag via
// in-wave shuffle web (2 shfl + 1 select per word). NO activation LDS, ONE
// barrier, zero bank-conflict-prone traffic. Bias folded into MFMA C-in.
// Layout law: D lane(lr,hi) holds feature nt*16+4*hi+q of edge-row 16w+lr;
// B-frag lane(lr,hi) needs features ks*32+hi*8+0..7 of row 16w+lr
//   = P[2ks+(hi>>1)][j&1] from lane lr+16*(2*(hi&1)+(j>>1)).
// ---------------------------------------------------------------------------
__global__ __launch_bounds__(256, 4)
void k_phase1(const float* __restrict__ x,
              const float* __restrict__ b1, const short* __restrict__ W1T,
              const short* __restrict__ W2T, const float* __restrict__ b2,
              const short* __restrict__ W3T, const float* __restrict__ b3,
              const float* __restrict__ W4T, const float* __restrict__ b4,
              short* __restrict__ outb, float* __restrict__ diagpart)
{
    __shared__ float feat[64][4];             // 1 KB — the only LDS
    const int t = threadIdx.x;
    const int lane = t & 63;
    const int w = t >> 6;                     // 0..3
    const int lr = lane & 15;
    const int hi = lane >> 4;
    const int b = blockIdx.x;
    const int bc = b / 63;                    // block-uniform
    const int r  = b - bc * 63;               // block-uniform
    const int row = w * 16 + lr;              // this lane's edge-row

    // ---- stage features: thread (row kk = t&63, feature q = t>>6) ----
    {
        int kk = t & 63, q = t >> 6;
        int jj = (kk + r + 1) & 63;
        const float* xb = x + bc * 4096;
        float v;
        if (q == 0)      v = xb[kk * 65];
        else if (q == 1) v = xb[kk * 64 + jj];
        else if (q == 2) v = xb[jj * 64 + kk];
        else             v = xb[jj * 65];
        feat[kk][q] = v;
    }
    __syncthreads();

    f32x4 acc[8];
    unsigned P[8][2];
    unsigned Bfr[4][4];

    // ---- L1 (MFMA, K=4 zero-padded to 32), bias in C ----
#pragma unroll
    for (int nt = 0; nt < 8; ++nt)
        acc[nt] = *(const f32x4*)(b1 + nt * 16 + 4 * hi);
    {
        u32x4 bw = {0u, 0u, 0u, 0u};
        if (hi == 0) {
            f32x4 fv = *(const f32x4*)(&feat[row][0]);
            bw[0] = cvt_pk_bf16(fv[0], fv[1]);
            bw[1] = cvt_pk_bf16(fv[2], fv[3]);
        }
        s16x8 bf = __builtin_bit_cast(s16x8, bw);
#pragma unroll
        for (int nt = 0; nt < 8; ++nt) {
            s16x8 aw = *(const s16x8*)(W1T + (nt * 16 + lr) * 32 + hi * 8);
            acc[nt] = __builtin_amdgcn_mfma_f32_16x16x32_bf16(aw, bf, acc[nt], 0, 0, 0);
        }
    }
#pragma unroll
    for (int nt = 0; nt < 8; ++nt) {
        P[nt][0] = cvt_pk_bf16(fmaxf(acc[nt][0], 0.f), fmaxf(acc[nt][1], 0.f));
        P[nt][1] = cvt_pk_bf16(fmaxf(acc[nt][2], 0.f), fmaxf(acc[nt][3], 0.f));
    }

    // ---- T1: P -> B fragments (in-register, no LDS) ----
#pragma unroll
    for (int ks = 0; ks < 4; ++ks)
#pragma unroll
        for (int j2 = 0; j2 < 2; ++j2) {
            int src = lr + 16 * (2 * (hi & 1) + j2);
#pragma unroll
            for (int h = 0; h < 2; ++h) {
                unsigned v0 = __shfl((int)P[2 * ks][h],     src, 64);
                unsigned v1 = __shfl((int)P[2 * ks + 1][h], src, 64);
                Bfr[ks][j2 * 2 + h] = (hi >> 1) ? v1 : v0;
            }
        }

    // ---- L2 (MFMA), bias in C ----
#pragma unroll
    for (int nt = 0; nt < 8; ++nt)
        acc[nt] = *(const f32x4*)(b2 + nt * 16 + 4 * hi);
#pragma unroll
    for (int ks = 0; ks < 4; ++ks) {
        s16x8 bf = __builtin_bit_cast(s16x8, *(const u32x4*)&Bfr[ks][0]);
#pragma unroll
        for (int nt = 0; nt < 8; ++nt) {
            s16x8 aw = *(const s16x8*)(W2T + (nt * 16 + lr) * 128 + ks * 32 + hi * 8);
            acc[nt] = __builtin_amdgcn_mfma_f32_16x16x32_bf16(aw, bf, acc[nt], 0, 0, 0);
        }
    }
#pragma unroll
    for (int nt = 0; nt < 8; ++nt) {
        P[nt][0] = cvt_pk_bf16(fmaxf(acc[nt][0], 0.f), fmaxf(acc[nt][1], 0.f));
        P[nt][1] = cvt_pk_bf16(fmaxf(acc[nt][2], 0.f), fmaxf(acc[nt][3], 0.f));
    }

    // ---- T2 ----
#pragma unroll
    for (int ks = 0; ks < 4; ++ks)
#pragma unroll
        for (int j2 = 0; j2 < 2; ++j2) {
            int src = lr + 16 * (2 * (hi & 1) + j2);
#pragma unroll
            for (int h = 0; h < 2; ++h) {
                unsigned v0 = __shfl((int)P[2 * ks][h],     src, 64);
                unsigned v1 = __shfl((int)P[2 * ks + 1][h], src, 64);
                Bfr[ks][j2 * 2 + h] = (hi >> 1) ? v1 : v0;
            }
        }

    // ---- L3 (MFMA), bias in C ----
#pragma unroll
    for (int nt = 0; nt < 8; ++nt)
        acc[nt] = *(const f32x4*)(b3 + nt * 16 + 4 * hi);
#pragma unroll
    for (int ks = 0; ks < 4; ++ks) {
        s16x8 bf = __builtin_bit_cast(s16x8, *(const u32x4*)&Bfr[ks][0]);
#pragma unroll
        for (int nt = 0; nt < 8; ++nt) {
            s16x8 aw = *(const s16x8*)(W3T + (nt * 16 + lr) * 128 + ks * 32 + hi * 8);
            acc[nt] = __builtin_amdgcn_mfma_f32_16x16x32_bf16(aw, bf, acc[nt], 0, 0, 0);
        }
    }

    // ---- L4 fused: dot over this lane's 32 features, reduce across hi ----
    {
        float s0 = 0.f, s1 = 0.f;
#pragma unroll
        for (int nt = 0; nt < 8; ++nt) {
            f32x4 w40 = *(const f32x4*)(W4T + nt * 16 + 4 * hi);
            f32x4 w41 = *(const f32x4*)(W4T + 128 + nt * 16 + 4 * hi);
#pragma unroll
            for (int q = 0; q < 4; ++q) {
                float h3 = fmaxf(acc[nt][q], 0.f);
                s0 = fmaf(h3, w40[q], s0);
                s1 = fmaf(h3, w41[q], s1);
            }
        }
        s0 += __shfl_xor(s0, 16, 64); s0 += __shfl_xor(s0, 32, 64);
        s1 += __shfl_xor(s1, 16, 64); s1 += __shfl_xor(s1, 32, 64);
        if (hi == 0) {
            int jj = (row + r + 1) & 63;
            outb[bc * 4096 + row * 64 + jj] = f2bf(s1 + b4[1]);  // off-diag (bf16)
            diagpart[b * 64 + row] = s0 + b4[0];                 // h0 for diag mean
        }
    }
}

// ---------------------------------------------------------------------------
// Diag: out[bc][k][k] = mean_r h0[bc][r][k]; coalesced rows, LDS reduce.
// ---------------------------------------------------------------------------
__global__ void k_diag(const float* __restrict__ diagpart, short* __restrict__ outb)
{
    __shared__ float rds[256];
    const int t = threadIdx.x, bcq = blockIdx.x;
    const int kx = t & 63, q = t >> 6;
    const float* p = diagpart + bcq * 4032 + kx;
    int r0 = q * 16, r1 = (r0 + 16 < 63) ? r0 + 16 : 63;
    float s = 0.f;
    for (int rr = r0; rr < r1; ++rr) s += p[rr * 64];
    rds[t] = s;
    __syncthreads();
    if (t < 64) {
        float v = (rds[t] + rds[t + 64] + rds[t + 128] + rds[t + 192]) * (1.0f / 63.0f);
        outb[bcq * 4096 + t * 65] = f2bf(v);
    }
}

// ---------------------------------------------------------------------------
// Fused channel MLP, 16-row tiles (grid 1024): one inner layer
// [16][K] bf16 LDS -> [16][N] bf16 LDS. 4 waves split N.
// ---------------------------------------------------------------------------
template<int K, int N, bool RELU>
__device__ __forceinline__ void chan_layer16(const short* src, const short* __restrict__ WT,
                                             const float* __restrict__ bias, short* dst,
                                             int w, int lr, int hi)
{
    constexpr int NF = N / 64;
    constexpr int KS = K / 32;
    const int n0 = w * (16 * NF);
    f32x4 acc[NF] = {};
#pragma unroll
    for (int ks = 0; ks < KS; ++ks) {
        const int kb = ks * 32 + hi * 8;
        s16x8 aw[NF];
#pragma unroll
        for (int nf = 0; nf < NF; ++nf)
            aw[nf] = *(const s16x8*)(WT + (n0 + nf * 16 + lr) * K + kb);
        int off = (lr * (K * 2) + kb * 2) ^ ((lr & 7) << 4);
        s16x8 bh = *(const s16x8*)((const char*)src + off);
#pragma unroll
        for (int nf = 0; nf < NF; ++nf)
            acc[nf] = __builtin_amdgcn_mfma_f32_16x16x32_bf16(aw[nf], bh, acc[nf], 0, 0, 0);
    }
#pragma unroll
    for (int nf = 0; nf < NF; ++nf) {
        f32x4 bv = *(const f32x4*)(bias + n0 + nf * 16 + 4 * hi);
        float v0 = acc[nf][0] + bv[0];
        float v1 = acc[nf][1] + bv[1];
        float v2 = acc[nf][2] + bv[2];
        float v3 = acc[nf][3] + bv[3];
        if (RELU) {
            v0 = fmaxf(v0, 0.f); v1 = fmaxf(v1, 0.f);
            v2 = fmaxf(v2, 0.f); v3 = fmaxf(v3, 0.f);
        }
        s16x4 pk = pack4(v0, v1, v2, v3);
        int off = (lr * (N * 2) + (n0 + nf * 16 + 4 * hi) * 2) ^ ((lr & 7) << 4);
        *(s16x4*)((char*)dst + off) = pk;
    }
}

__global__ __launch_bounds__(256, 6)
void k_chanfused(const short* __restrict__ outb,
                 const short* __restrict__ Wc1T, const float* __restrict__ bc1,
                 const short* __restrict__ Wc2T, const float* __restrict__ bc2,
                 const short* __restrict__ Wc3T, const float* __restrict__ bc3,
                 const short* __restrict__ Wc4T, const float* __restrict__ bc4,
                 float* __restrict__ out)
{
    __shared__ short bufA[16 * 256];   // 8 KB
    __shared__ short bufB[16 * 256];   // 8 KB
    __shared__ float redc[2][16][16];  // 2 KB c4 K-split partials
    const int t = threadIdx.x, lane = t & 63, w = t >> 6;
    const int lr = lane & 15, hi = lane >> 4;
    const int bb = blockIdx.x >> 8;
    const int nm0 = (blockIdx.x & 255) * 16;

    // stage A0: [16 rows][64 c], row stride 128B, swizzled
    {
        int c = t & 63, rq = t >> 6;
        s16x4 v = *(const s16x4*)(outb + ((size_t)(bb * 64 + c)) * 4096 + nm0 + rq * 4);
#pragma unroll
        for (int q = 0; q < 4; ++q) {
            int row = rq * 4 + q;
            int off = (row * 128 + c * 2) ^ ((row & 7) << 4);
            *(short*)((char*)bufA + off) = v[q];
        }
    }
    __syncthreads();
    chan_layer16< 64, 128, true>(bufA, Wc1T, bc1, bufB, w, lr, hi);
    __syncthreads();
    chan_layer16<128, 256, true>(bufB, Wc2T, bc2, bufA, w, lr, hi);
    __syncthreads();
    chan_layer16<256, 256, true>(bufA, Wc3T, bc3, bufB, w, lr, hi);
    __syncthreads();

    // c4: K=256 split across wave pairs (wk), N=32 split wn; fp32 out.
    {
        const int wn = w & 1, wk = w >> 1;
        const int n0 = wn * 16;
        f32x4 acc = {};
#pragma unroll
        for (int ks = 0; ks < 4; ++ks) {
            const int kb = (wk * 4 + ks) * 32 + hi * 8;
            s16x8 aw = *(const s16x8*)(Wc4T + (n0 + lr) * 256 + kb);
            int off = (lr * 512 + kb * 2) ^ ((lr & 7) << 4);
            s16x8 bh = *(const s16x8*)((const char*)bufB + off);
            acc = __builtin_amdgcn_mfma_f32_16x16x32_bf16(aw, bh, acc, 0, 0, 0);
        }
        if (wk == 1) {
#pragma unroll
            for (int q = 0; q < 4; ++q)
                redc[wn][4 * hi + q][lr] = acc[q];
        }
        __syncthreads();
        if (wk == 0) {
            f32x4 bv = *(const f32x4*)(bc4 + n0 + 4 * hi);
#pragma unroll
            for (int q = 0; q < 4; ++q) {
                int n = n0 + 4 * hi + q;
                out[((size_t)(bb * 32 + n)) * 4096 + nm0 + lr] =
                    acc[q] + redc[wn][4 * hi + q][lr] + bv[q];
            }
        }
    }
}

// ---------------------------------------------------------------------------
extern "C" void kernel_launch(void* const* d_in, const int* in_sizes, int n_in,
                              void* d_out, int out_size, void* d_ws, size_t ws_size,
                              hipStream_t stream)
{
    const float* x   = (const float*)d_in[0];
    const float* W1  = (const float*)d_in[1];
    const float* b1  = (const float*)d_in[2];
    const float* W2  = (const float*)d_in[3];
    const float* b2  = (const float*)d_in[4];
    const float* W3  = (const float*)d_in[5];
    const float* b3  = (const float*)d_in[6];
    const float* W4  = (const float*)d_in[7];
    const float* b4  = (const float*)d_in[8];
    const float* Wc1 = (const float*)d_in[9];
    const float* bc1 = (const float*)d_in[10];
    const float* Wc2 = (const float*)d_in[11];
    const float* bc2 = (const float*)d_in[12];
    const float* Wc3 = (const float*)d_in[13];
    const float* bc3 = (const float*)d_in[14];
    const float* Wc4 = (const float*)d_in[15];
    const float* bc4 = (const float*)d_in[16];
    float* out = (float*)d_out;

    char* ws = (char*)d_ws;
    // [0,2M) outb bf16 | [2M,8M) diagpart | [8M,...) weights
    short* outb     = (short*)(ws);
    float* diagpart = (float*)(ws + (2u << 20));

    size_t off = 8u << 20;
    short* W1T  = (short*)(ws + off); off += 4096 * 2;
    short* W2T  = (short*)(ws + off); off += 16384 * 2;
    short* W3T  = (short*)(ws + off); off += 16384 * 2;
    short* Wc1T = (short*)(ws + off); off += 8192 * 2;
    short* Wc2T = (short*)(ws + off); off += 32768 * 2;
    short* Wc3T = (short*)(ws + off); off += 65536 * 2;
    short* Wc4T = (short*)(ws + off); off += 8192 * 2;
    float* W4T  = (float*)(ws + off); off += 256 * 4;

    k_prep<<<256, 256, 0, stream>>>(W1, W2, W3, W4, Wc1, Wc2, Wc3, Wc4,
                                    W1T, W2T, W3T, W4T, Wc1T, Wc2T, Wc3T, Wc4T);
    k_phase1<<<16128, 256, 0, stream>>>(x, b1, W1T, W2T, b2, W3T, b3, W4T, b4,
                                        outb, diagpart);
    k_diag<<<256, 256, 0, stream>>>(diagpart, outb);
    k_chanfused<<<1024, 256, 0, stream>>>(outb, Wc1T, bc1, Wc2T, bc2,
                                          Wc3T, bc3, Wc4T, bc4, out);
}